// Round 13
// baseline (264.536 us; speedup 1.0000x reference)
//
#include <hip/hip_runtime.h>

#define N_NODES 100000
#define NT (2 * N_NODES)             // stacked nodes (conv1 then conv2)
#define D 128
#define N_EDGES 600000
#define ET (2 * N_EDGES)
#define CAP 32                       // ELL capacity; P(deg>32)~1e-15 (Poisson(6))
#define XBLK 12500                   // x2bf blocks
#define EGRID ((ET + 255) / 256)     // 4688 edge blocks
#define FROWS 64                     // rows per fused block (4 waves)
#define FBLK ((N_NODES + FROWS - 1) / FROWS) // 1563
#define NBLK2 ((NT + 255) / 256)     // 782

typedef __attribute__((ext_vector_type(8))) short bf16x8;
typedef __attribute__((ext_vector_type(4))) float f32x4;

__device__ __forceinline__ unsigned short f2bf(float f) {
    union { float f; unsigned u; } v; v.f = f;
    unsigned r = (v.u + 0x7fff + ((v.u >> 16) & 1)) >> 16;   // RNE
    return (unsigned short)r;
}
__device__ __forceinline__ float bf2f(unsigned short h) {
    union { unsigned u; float f; } v; v.u = ((unsigned)h) << 16;
    return v.f;
}

// ---------- edge index dtype handling ----------
__device__ __forceinline__ long long load_idx(const void* e, long long i, int is32) {
    if (is32) return (long long)((const int*)e)[i];
    return ((const long long*)e)[i];
}

// per-wave redundant dtype detect: 64 L2-hot samples, no cross-kernel dependency
__device__ __forceinline__ int self_detect(const unsigned long long* __restrict__ e) {
    unsigned long long v = e[threadIdx.x & 63];
    unsigned long long m = __ballot(v > 0xFFFFFFFFull);
    return (m != 0ull) ? 1 : 0;
}

// ---------- K1: Mt (0..127) | bt (128) | x2bf (129..12628) | degree+ELL (rest) ----------
__global__ void prep_x2bf_ell(const float* __restrict__ W1, const float* __restrict__ W2,
                              const float* __restrict__ weight,
                              const float* __restrict__ b1, const float* __restrict__ b2,
                              const float* __restrict__ bias,
                              const float* __restrict__ x, unsigned short* __restrict__ xb,
                              const void* __restrict__ ep, const void* __restrict__ en,
                              unsigned short* __restrict__ Mt, float* __restrict__ bt,
                              int* __restrict__ cnt, unsigned* __restrict__ ell) {
    const int b = blockIdx.x;
    if (b < 128) {
        // Mt[j][k] bf16: j=out col (128), k=stacked contraction (256)
        int idx = b * 256 + threadIdx.x;
        int j = idx >> 8, k = idx & 255;
        float a = 0.f;
        if (k < D) {
            for (int d = 0; d < D; ++d) a += W1[k * D + d] * weight[d * D + j];
        } else {
            for (int d = 0; d < D; ++d) a += W2[(k - D) * D + d] * weight[(D + d) * D + j];
        }
        Mt[j * 256 + k] = f2bf(a);
    } else if (b == 128) {
        int t = threadIdx.x;
        if (t < D) {
            float a = bias[t];
            for (int k = 0; k < D; ++k)
                a += b1[k] * weight[k * D + t] + b2[k] * weight[(D + k) * D + t];
            bt[t] = a;
        }
    } else if (b < 129 + XBLK) {
        long long t = (long long)(b - 129) * 256 + threadIdx.x;   // N*32 float4 slots
        float4 a = ((const float4*)x)[t];
        ((ushort4*)xb)[t] = make_ushort4(f2bf(a.x), f2bf(a.y), f2bf(a.z), f2bf(a.w));
    } else {
        int is32 = self_detect((const unsigned long long*)ep);
        int i = (b - 129 - XBLK) * 256 + threadIdx.x;
        if (i >= ET) return;
        int conv = (i >= N_EDGES);
        const void* e = conv ? en : ep;
        int j = conv ? i - N_EDGES : i;
        int si = (int)load_idx(e, j, is32);
        int di = (int)load_idx(e, (long long)N_EDGES + j, is32);
        int node = conv * N_NODES + di;
        int slot = atomicAdd(&cnt[node], 1);    // cnt doubles as degree after pass
        if (slot < CAP) ell[(size_t)node * CAP + slot] = (unsigned)si;
    }
}

// ---------- dinv = rsqrt(deg+1) ----------
__global__ void make_dinv(const int* __restrict__ cnt, float* __restrict__ dinv) {
    int i = blockIdx.x * 256 + threadIdx.x;
    if (i < NT) dinv[i] = rsqrtf((float)cnt[i] + 1.0f);
}

// ---------- fused gather + GEMM (no LDS: Mt is L2-resident, read B-frags direct) ----------
// 256 threads = 4 waves; wave w owns output rows [blk*64 + 16w, +16).
// Lane l (rl=l&15, q=l>>4) gathers row blk*64+16w+rl, cols q*8 + {0,32,64,96}.
__global__ __launch_bounds__(256) void fused_gather_gemm(
    const int* __restrict__ cnt, const unsigned* __restrict__ ell,
    const unsigned short* __restrict__ xb, const float* __restrict__ dinv,
    const unsigned short* __restrict__ Mt, const float* __restrict__ bt,
    float* __restrict__ out) {
    int t = threadIdx.x;
    int wave = t >> 6, lane = t & 63;
    int rl = lane & 15, q = lane >> 4;
    int gr = blockIdx.x * FROWS + wave * 16 + rl;        // gathered row
    const bool valid = gr < N_NODES;

    f32x4 C[8];
    #pragma unroll
    for (int i = 0; i < 8; ++i) C[i] = (f32x4){0.f, 0.f, 0.f, 0.f};

    #pragma unroll
    for (int conv = 0; conv < 2; ++conv) {
        float acc[4][8];
        if (valid) {
            int n = conv * N_NODES + gr;
            float dn = dinv[n];
            float f = dn * dn;
            const unsigned short* xr = xb + (size_t)gr * D + q * 8;
            #pragma unroll
            for (int m = 0; m < 4; ++m) {
                bf16x8 v = *(const bf16x8*)(xr + m * 32);
                #pragma unroll
                for (int j = 0; j < 8; ++j) acc[m][j] = bf2f((unsigned short)v[j]) * f;
            }
            int deg = cnt[n];
            if (deg > CAP) deg = CAP;                    // overflow guard
            const unsigned* ep = ell + (size_t)n * CAP;
            const float* dsrc = dinv + (size_t)conv * N_NODES;   // FIX (R12 bug):
            for (int e = 0; e < deg; ++e) {                      // source dinv must use
                unsigned si = ep[e];                             // the STACKED index
                float co = dn * dsrc[si];                        // conv*N + si
                const unsigned short* xs = xb + (size_t)si * D + q * 8;
                #pragma unroll
                for (int m = 0; m < 4; ++m) {
                    bf16x8 v = *(const bf16x8*)(xs + m * 32);
                    #pragma unroll
                    for (int j = 0; j < 8; ++j) acc[m][j] += co * bf2f((unsigned short)v[j]);
                }
            }
        } else {
            #pragma unroll
            for (int m = 0; m < 4; ++m)
                #pragma unroll
                for (int j = 0; j < 8; ++j) acc[m][j] = 0.f;
        }
        // convert + MFMA per k-fragment (B read from global: L2-hot broadcast)
        #pragma unroll
        for (int m = 0; m < 4; ++m) {
            bf16x8 a;
            #pragma unroll
            for (int j = 0; j < 8; ++j) a[j] = (short)f2bf(acc[m][j]);
            const unsigned short* Bp = Mt + (size_t)rl * 256 + conv * 128 + m * 32 + q * 8;
            #pragma unroll
            for (int ct = 0; ct < 8; ++ct) {
                bf16x8 bfr = *(const bf16x8*)(Bp + (size_t)ct * 16 * 256);
                C[ct] = __builtin_amdgcn_mfma_f32_16x16x32_bf16(a, bfr, C[ct], 0, 0, 0);
            }
        }
    }

    // C/D layout: col = lane&15, row = (lane>>4)*4 + reg
    int orow = blockIdx.x * FROWS + wave * 16 + q * 4;
    #pragma unroll
    for (int ct = 0; ct < 8; ++ct) {
        int col = ct * 16 + rl;
        float b = bt[col];
        #pragma unroll
        for (int reg = 0; reg < 4; ++reg) {
            int row = orow + reg;
            if (row < N_NODES) out[(long long)row * D + col] = C[ct][reg] + b;
        }
    }
}

extern "C" void kernel_launch(void* const* d_in, const int* in_sizes, int n_in,
                              void* d_out, int out_size, void* d_ws, size_t ws_size,
                              hipStream_t stream) {
    const float* x      = (const float*)d_in[0];
    const void*  e_pos  = d_in[1];
    const void*  e_neg  = d_in[2];
    const float* W1     = (const float*)d_in[3];
    const float* b1     = (const float*)d_in[4];
    const float* W2     = (const float*)d_in[5];
    const float* b2     = (const float*)d_in[6];
    const float* weight = (const float*)d_in[7];
    const float* bias   = (const float*)d_in[8];
    float* out = (float*)d_out;

    // ---- workspace layout (~53 MB) ----
    unsigned short* xb = (unsigned short*)d_ws;          // N*D bf16 (25.6 MB)
    unsigned short* Mt = xb + (size_t)N_NODES * D;       // 128*256 (64 KB)
    float* bt   = (float*)(Mt + 128 * 256);              // D
    float* dinv = bt + D;                                // NT (800 KB)
    int*   cnt  = (int*)(dinv + NT);                     // NT (800 KB)
    unsigned* ell = (unsigned*)(cnt + NT);               // NT*CAP (25.6 MB)

    hipMemsetAsync(cnt, 0, NT * sizeof(int), stream);
    prep_x2bf_ell<<<129 + XBLK + EGRID, 256, 0, stream>>>(
        W1, W2, weight, b1, b2, bias, x, xb, e_pos, e_neg, Mt, bt, cnt, ell);
    make_dinv<<<NBLK2, 256, 0, stream>>>(cnt, dinv);
    fused_gather_gemm<<<FBLK, 256, 0, stream>>>(cnt, ell, xb, dinv, Mt, bt, out);
}

// Round 14
// 237.350 us; speedup vs baseline: 1.1145x; 1.1145x over previous
//
#include <hip/hip_runtime.h>

#define N_NODES 100000
#define NT (2 * N_NODES)             // stacked nodes (conv1 then conv2)
#define D 128
#define N_EDGES 600000
#define ET (2 * N_EDGES)
#define CAP 32                       // ELL capacity; P(deg>32)~1e-15 (Poisson(6))
#define XBLK 12500                   // x2bf blocks
#define EGRID ((ET + 255) / 256)     // 4688 edge blocks
#define FROWS 256                    // rows per fused block (16 waves)
#define FBLK ((N_NODES + FROWS - 1) / FROWS) // 391
#define NBLK2 ((NT + 255) / 256)     // 782

typedef __attribute__((ext_vector_type(8))) short bf16x8;
typedef __attribute__((ext_vector_type(4))) float f32x4;

__device__ __forceinline__ unsigned short f2bf(float f) {
    union { float f; unsigned u; } v; v.f = f;
    unsigned r = (v.u + 0x7fff + ((v.u >> 16) & 1)) >> 16;   // RNE
    return (unsigned short)r;
}
__device__ __forceinline__ float bf2f(unsigned short h) {
    union { unsigned u; float f; } v; v.u = ((unsigned)h) << 16;
    return v.f;
}

// ---------- edge index dtype handling ----------
__device__ __forceinline__ long long load_idx(const void* e, long long i, int is32) {
    if (is32) return (long long)((const int*)e)[i];
    return ((const long long*)e)[i];
}

// per-wave redundant dtype detect: 64 L2-hot samples, no cross-kernel dependency
__device__ __forceinline__ int self_detect(const unsigned long long* __restrict__ e) {
    unsigned long long v = e[threadIdx.x & 63];
    unsigned long long m = __ballot(v > 0xFFFFFFFFull);
    return (m != 0ull) ? 1 : 0;
}

// ---------- K1: Mt (0..127) | bt (128) | x2bf (129..12628) | degree (rest) ----------
__global__ void prep_x2bf_degree(const float* __restrict__ W1, const float* __restrict__ W2,
                                 const float* __restrict__ weight,
                                 const float* __restrict__ b1, const float* __restrict__ b2,
                                 const float* __restrict__ bias,
                                 const float* __restrict__ x, unsigned short* __restrict__ xb,
                                 const void* __restrict__ ep, const void* __restrict__ en,
                                 unsigned short* __restrict__ Mt, float* __restrict__ bt,
                                 int* __restrict__ cnt) {
    const int b = blockIdx.x;
    if (b < 128) {
        // Mt[j][k] bf16: j=out col (128), k=stacked contraction (256)
        int idx = b * 256 + threadIdx.x;
        int j = idx >> 8, k = idx & 255;
        float a = 0.f;
        if (k < D) {
            for (int d = 0; d < D; ++d) a += W1[k * D + d] * weight[d * D + j];
        } else {
            for (int d = 0; d < D; ++d) a += W2[(k - D) * D + d] * weight[(D + d) * D + j];
        }
        Mt[j * 256 + k] = f2bf(a);
    } else if (b == 128) {
        int t = threadIdx.x;
        if (t < D) {
            float a = bias[t];
            for (int k = 0; k < D; ++k)
                a += b1[k] * weight[k * D + t] + b2[k] * weight[(D + k) * D + t];
            bt[t] = a;
        }
    } else if (b < 129 + XBLK) {
        long long t = (long long)(b - 129) * 256 + threadIdx.x;   // N*32 float4 slots
        float4 a = ((const float4*)x)[t];
        ((ushort4*)xb)[t] = make_ushort4(f2bf(a.x), f2bf(a.y), f2bf(a.z), f2bf(a.w));
    } else {
        int is32 = self_detect((const unsigned long long*)ep);
        int i = (b - 129 - XBLK) * 256 + threadIdx.x;
        if (i >= ET) return;
        int conv = (i >= N_EDGES);
        const void* e = conv ? en : ep;
        int j = conv ? i - N_EDGES : i;
        long long d = load_idx(e, (long long)N_EDGES + j, is32);
        atomicAdd(&cnt[conv * N_NODES + (int)d], 1);
    }
}

// ---------- dinv = rsqrt(deg+1), degb = clamp(deg,255) ----------
__global__ void make_dinv(const int* __restrict__ cnt, float* __restrict__ dinv,
                          unsigned char* __restrict__ degb) {
    int i = blockIdx.x * 256 + threadIdx.x;
    if (i < NT) {
        int v = cnt[i];
        dinv[i] = rsqrtf((float)v + 1.0f);
        degb[i] = (unsigned char)(v > 255 ? 255 : v);
    }
}

// ---------- ELL fill: packed {src:20b | deg(src):8b}; cnt used as countdown ----------
// After this pass cnt is exactly 0 for every node (deg decrements of deg).
__global__ void ell_fill(const void* __restrict__ ep_, const void* __restrict__ en_,
                         const unsigned char* __restrict__ degb,
                         int* __restrict__ cnt, unsigned* __restrict__ ell) {
    int is32 = self_detect((const unsigned long long*)ep_);
    int i = blockIdx.x * blockDim.x + threadIdx.x;
    if (i >= ET) return;
    int conv = (i >= N_EDGES);
    const void* e = conv ? en_ : ep_;
    int j = conv ? i - N_EDGES : i;
    int si = (int)load_idx(e, j, is32);
    int di = (int)load_idx(e, (long long)N_EDGES + j, is32);
    int g = conv * N_NODES;
    int node = g + di;
    int slot = atomicSub(&cnt[node], 1) - 1;   // slots deg-1..0
    if (slot >= 0 && slot < CAP) {
        unsigned degS = degb[g + si];
        ell[(size_t)node * CAP + slot] = (unsigned)si | (degS << 20);
    }
}

// ---------- fused gather + GEMM (R11-proven shape; ELL-fed) ----------
// 1024 threads = 16 waves sharing one 66KB Mt LDS copy; wave w owns output rows
// [blk*256 + 16w, +16). Lane l (rl=l&15, q=l>>4) gathers row blk*256+16w+rl,
// cols q*8 + {0,32,64,96} — exactly its 8 MFMA A-fragments. Edge loop unroll x2.
// Coef is VALU-only (deg packed in entry) — no random dinv load (R13 lesson).
__global__ __launch_bounds__(1024) void fused_gather_gemm(
    const unsigned char* __restrict__ degb, const unsigned* __restrict__ ell,
    const unsigned short* __restrict__ xb, const float* __restrict__ dinv,
    const unsigned short* __restrict__ Mt, const float* __restrict__ bt,
    float* __restrict__ out) {
    __shared__ unsigned short mlds[128][264];   // +8 pad
    int t = threadIdx.x;
    for (int c = t; c < 4096; c += 1024) {
        int row = c >> 5;
        int kc = (c & 31) * 8;
        *(ulonglong2*)&mlds[row][kc] = *(const ulonglong2*)&Mt[row * 256 + kc];
    }
    __syncthreads();

    int wave = t >> 6, lane = t & 63;
    int rl = lane & 15, q = lane >> 4;
    int gr = blockIdx.x * FROWS + wave * 16 + rl;        // gathered row
    const bool valid = gr < N_NODES;

    bf16x8 af[8];
    #pragma unroll
    for (int conv = 0; conv < 2; ++conv) {
        float acc[4][8];
        if (valid) {
            int n = conv * N_NODES + gr;
            float dn = dinv[n];
            float f = dn * dn;
            const unsigned short* xr = xb + (size_t)gr * D + q * 8;
            #pragma unroll
            for (int m = 0; m < 4; ++m) {
                bf16x8 v = *(const bf16x8*)(xr + m * 32);
                #pragma unroll
                for (int j = 0; j < 8; ++j) acc[m][j] = bf2f((unsigned short)v[j]) * f;
            }
            int deg = degb[n];
            if (deg > CAP) deg = CAP;                    // overflow guard
            const unsigned* ep = ell + (size_t)n * CAP;
            int e = 0;
            for (; e + 1 < deg; e += 2) {
                unsigned c0 = ep[e], c1 = ep[e + 1];
                const unsigned short* p0 = xb + (size_t)(c0 & 0xFFFFF) * D + q * 8;
                const unsigned short* p1 = xb + (size_t)(c1 & 0xFFFFF) * D + q * 8;
                bf16x8 a0 = *(const bf16x8*)(p0);
                bf16x8 a1 = *(const bf16x8*)(p0 + 32);
                bf16x8 a2 = *(const bf16x8*)(p0 + 64);
                bf16x8 a3 = *(const bf16x8*)(p0 + 96);
                bf16x8 b0 = *(const bf16x8*)(p1);
                bf16x8 b1 = *(const bf16x8*)(p1 + 32);
                bf16x8 b2 = *(const bf16x8*)(p1 + 64);
                bf16x8 b3 = *(const bf16x8*)(p1 + 96);
                float coef0 = dn * rsqrtf((float)(c0 >> 20) + 1.0f);
                float coef1 = dn * rsqrtf((float)(c1 >> 20) + 1.0f);
                #pragma unroll
                for (int j = 0; j < 8; ++j) {
                    acc[0][j] += coef0 * bf2f((unsigned short)a0[j]);
                    acc[1][j] += coef0 * bf2f((unsigned short)a1[j]);
                    acc[2][j] += coef0 * bf2f((unsigned short)a2[j]);
                    acc[3][j] += coef0 * bf2f((unsigned short)a3[j]);
                }
                #pragma unroll
                for (int j = 0; j < 8; ++j) {
                    acc[0][j] += coef1 * bf2f((unsigned short)b0[j]);
                    acc[1][j] += coef1 * bf2f((unsigned short)b1[j]);
                    acc[2][j] += coef1 * bf2f((unsigned short)b2[j]);
                    acc[3][j] += coef1 * bf2f((unsigned short)b3[j]);
                }
            }
            if (e < deg) {
                unsigned c0 = ep[e];
                const unsigned short* p0 = xb + (size_t)(c0 & 0xFFFFF) * D + q * 8;
                bf16x8 a0 = *(const bf16x8*)(p0);
                bf16x8 a1 = *(const bf16x8*)(p0 + 32);
                bf16x8 a2 = *(const bf16x8*)(p0 + 64);
                bf16x8 a3 = *(const bf16x8*)(p0 + 96);
                float coef0 = dn * rsqrtf((float)(c0 >> 20) + 1.0f);
                #pragma unroll
                for (int j = 0; j < 8; ++j) {
                    acc[0][j] += coef0 * bf2f((unsigned short)a0[j]);
                    acc[1][j] += coef0 * bf2f((unsigned short)a1[j]);
                    acc[2][j] += coef0 * bf2f((unsigned short)a2[j]);
                    acc[3][j] += coef0 * bf2f((unsigned short)a3[j]);
                }
            }
        } else {
            #pragma unroll
            for (int m = 0; m < 4; ++m)
                #pragma unroll
                for (int j = 0; j < 8; ++j) acc[m][j] = 0.f;
        }
        #pragma unroll
        for (int m = 0; m < 4; ++m) {
            bf16x8 a;
            #pragma unroll
            for (int j = 0; j < 8; ++j) a[j] = (short)f2bf(acc[m][j]);
            af[conv * 4 + m] = a;
        }
    }

    f32x4 C[8];
    #pragma unroll
    for (int i = 0; i < 8; ++i) C[i] = (f32x4){0.f, 0.f, 0.f, 0.f};
    #pragma unroll
    for (int ks = 0; ks < 8; ++ks) {
        bf16x8 afr = af[ks];          // ks 0..3 -> conv1 k-blocks, 4..7 -> conv2
        #pragma unroll
        for (int ct = 0; ct < 8; ++ct) {
            bf16x8 bfr = *(const bf16x8*)&mlds[ct * 16 + rl][ks * 32 + q * 8];
            C[ct] = __builtin_amdgcn_mfma_f32_16x16x32_bf16(afr, bfr, C[ct], 0, 0, 0);
        }
    }

    // C/D layout: col = lane&15, row = (lane>>4)*4 + reg
    int orow = blockIdx.x * FROWS + wave * 16 + q * 4;
    #pragma unroll
    for (int ct = 0; ct < 8; ++ct) {
        int col = ct * 16 + rl;
        float b = bt[col];
        #pragma unroll
        for (int reg = 0; reg < 4; ++reg) {
            int row = orow + reg;
            if (row < N_NODES) out[(long long)row * D + col] = C[ct][reg] + b;
        }
    }
}

extern "C" void kernel_launch(void* const* d_in, const int* in_sizes, int n_in,
                              void* d_out, int out_size, void* d_ws, size_t ws_size,
                              hipStream_t stream) {
    const float* x      = (const float*)d_in[0];
    const void*  e_pos  = d_in[1];
    const void*  e_neg  = d_in[2];
    const float* W1     = (const float*)d_in[3];
    const float* b1     = (const float*)d_in[4];
    const float* W2     = (const float*)d_in[5];
    const float* b2     = (const float*)d_in[6];
    const float* weight = (const float*)d_in[7];
    const float* bias   = (const float*)d_in[8];
    float* out = (float*)d_out;

    // ---- workspace layout (~54 MB) ----
    unsigned short* xb = (unsigned short*)d_ws;          // N*D bf16 (25.6 MB)
    unsigned short* Mt = xb + (size_t)N_NODES * D;       // 128*256 (64 KB)
    float* bt   = (float*)(Mt + 128 * 256);              // D
    float* dinv = bt + D;                                // NT (800 KB)
    int*   cnt  = (int*)(dinv + NT);                     // NT (800 KB)
    unsigned char* degb = (unsigned char*)(cnt + NT);    // NT bytes (200 KB)
    unsigned* ell = (unsigned*)(degb + NT);              // NT*CAP (25.6 MB)

    hipMemsetAsync(cnt, 0, NT * sizeof(int), stream);
    prep_x2bf_degree<<<129 + XBLK + EGRID, 256, 0, stream>>>(
        W1, W2, weight, b1, b2, bias, x, xb, e_pos, e_neg, Mt, bt, cnt);
    make_dinv<<<NBLK2, 256, 0, stream>>>(cnt, dinv, degb);
    ell_fill<<<EGRID, 256, 0, stream>>>(e_pos, e_neg, degb, cnt, ell);
    fused_gather_gemm<<<FBLK, 1024, 0, stream>>>(degb, ell, xb, dinv, Mt, bt, out);
}